// Round 19
// baseline (1607.914 us; speedup 1.0000x reference)
//
#include <hip/hip_runtime.h>
#include <hip/hip_bf16.h>

// R19: the INLINING law. Across all 19 builds: every no-spill 124-128-VGPR
// compile (R2,R4,R5,R6,R11,R13) had the phase body in a NOINLINE templated
// function; every spilling build (R15,R17,R18 -- 222MB FETCH/phase at cap
// 128) had it fully inlined into a kernel with runtime l/axis/parity
// plumbing (demand ~204: the allocator drags ~80 caller values across the
// hot loops). Fix: R18's plain-launch structure (512 blocks x 512 threads,
// kernel-boundary sync, 8 phase launches) + the R5/R6-style noinline body
// (template FIRST, pointers computed in caller and passed as args -- the
// exact call shape that compiled 124-128/no-spill six times). At <=128 VGPR:
// 4 waves/SIMD -> 2 blocks/CU -> 16 waves/CU, all 512 blocks resident.
// Gates: per-phase FETCH ~10-25MB (no spill); >=100MB -> revert to R14
// (770us) as terminal. enc/cls untouched.
#define NBAT 128
#define SS   48
#define DD   8
#define HDIM 8
#define NL   8
#define NC   7
#define PIX  (SS*SS)
#define RGN  (PIX*DD)            // one exchange region: 18432 floats
#define GBAT (2*RGN)             // row+col regions per batch
#define BUFSZ ((size_t)NBAT*GBAT)      // one parity buffer (floats)
#define KVV  384
#define KVW  768
#define PBDIM 512                // phase block: 8 waves
#define NWAV  8

__device__ __forceinline__ float ldsel(const void* p, long i, bool bf) {
    return bf ? __bfloat162float(((const __hip_bfloat16*)p)[i])
              : ((const float*)p)[i];
}

__device__ __forceinline__ bool sniff_bf(const void* xv) {
    const unsigned* xu = (const unsigned*)xv;
    int cnt = 0;
    #pragma unroll
    for (int t = 0; t < 32; ++t) {
        const unsigned w = xu[t];
        const int e = (w >> 7) & 0xff;
        cnt += (e > 100 && e < 150) ? 1 : 0;
    }
    return cnt >= 20;
}

// ---------------------------------------------------------------------------
// The noinline phase body (R5/R6 call shape): 3 problems for this wave.
// own = this orientation's region (self-written, coalesced (prob*SS+tl));
// oth = opposite region ((tl*SS+prob), scattered, L2-absorbed).
// FIRST=1: layer 0, ht = h0 as-is (no relu-add).
template <int FIRST>
__device__ __attribute__((noinline))
void attn_body_f(const float4* __restrict__ own, const float4* __restrict__ oth,
                 float4* __restrict__ gout, float* __restrict__ kvw,
                 const float* __restrict__ wb, int pbase, int wav, int lane, int tl)
{
    const float4* kv4 = reinterpret_cast<const float4*>(kvw);
    #pragma unroll 1
    for (int p = 0; p < 3; ++p) {
        const int prob = pbase + wav + p*NWAV;
        const int aown = (prob*SS + tl)*2;

        float ht[DD];
        {
            const float4 o0 = own[aown], o1 = own[aown+1];
            if (FIRST) {
                ht[0]=o0.x; ht[1]=o0.y; ht[2]=o0.z; ht[3]=o0.w;
                ht[4]=o1.x; ht[5]=o1.y; ht[6]=o1.z; ht[7]=o1.w;
            } else {
                const int aoth = (tl*SS + prob)*2;
                const float4 t0 = oth[aoth], t1 = oth[aoth+1];
                ht[0]=fmaxf(0.f,o0.x+t0.x); ht[1]=fmaxf(0.f,o0.y+t0.y);
                ht[2]=fmaxf(0.f,o0.z+t0.z); ht[3]=fmaxf(0.f,o0.w+t0.w);
                ht[4]=fmaxf(0.f,o1.x+t1.x); ht[5]=fmaxf(0.f,o1.y+t1.y);
                ht[6]=fmaxf(0.f,o1.z+t1.z); ht[7]=fmaxf(0.f,o1.w+t1.w);
            }
        }

        // q/k/v projections; fold 0.5 (E^-0.5) * log2(e) into q for exp2.
        float q[HDIM];
        {
            float kk[HDIM], vv[HDIM];
            #pragma unroll
            for (int o = 0; o < HDIM; ++o) {
                float aq = 0.f, ak = 0.f, av = 0.f;
                #pragma unroll
                for (int d = 0; d < DD; ++d) {
                    aq += ht[d] * wb[o*8 + d];
                    ak += ht[d] * wb[64 + o*8 + d];
                    av += ht[d] * wb[128 + o*8 + d];
                }
                q[o] = aq * 0.72134752044f;  // 0.5 * log2(e)
                kk[o] = ak; vv[o] = av;
            }
            if (lane < SS) {   // lanes 48-63 would duplicate token 47: skip
                float4* kp = reinterpret_cast<float4*>(kvw + tl*8);
                kp[0] = make_float4(kk[0], kk[1], kk[2], kk[3]);
                kp[1] = make_float4(kk[4], kk[5], kk[6], kk[7]);
                float4* vp = reinterpret_cast<float4*>(kvw + KVV + tl*8);
                vp[0] = make_float4(vv[0], vv[1], vv[2], vv[3]);
                vp[1] = make_float4(vv[4], vv[5], vv[6], vv[7]);
            }
        }

        float ov[HDIM];
        #pragma unroll
        for (int hh = 0; hh < 2; ++hh) {
            float dt[SS];
            #pragma unroll
            for (int j2 = 0; j2 < SS; ++j2) {
                const float4 kk4 = kv4[j2*2 + hh];       // LDS same-addr broadcast
                float acc =  q[hh*4+0] * kk4.x;
                acc       += q[hh*4+1] * kk4.y;
                acc       += q[hh*4+2] * kk4.z;
                acc       += q[hh*4+3] * kk4.w;
                dt[j2] = acc;
            }
            // max tree (fmax exactly associative -> bitwise same as chain)
            float mt[24];
            #pragma unroll
            for (int t2 = 0; t2 < 24; ++t2) mt[t2] = fmaxf(dt[t2], dt[t2+24]);
            #pragma unroll
            for (int t2 = 0; t2 < 12; ++t2) mt[t2] = fmaxf(mt[t2], mt[t2+12]);
            #pragma unroll
            for (int t2 = 0; t2 < 6; ++t2)  mt[t2] = fmaxf(mt[t2], mt[t2+6]);
            #pragma unroll
            for (int t2 = 0; t2 < 3; ++t2)  mt[t2] = fmaxf(mt[t2], mt[t2+3]);
            const float m = fmaxf(fmaxf(mt[0], mt[1]), mt[2]);
            float s = 0.f;
            #pragma unroll
            for (int j2 = 0; j2 < SS; ++j2) {
                float pv = exp2f(dt[j2] - m);
                dt[j2] = pv; s += pv;
            }
            float o0 = 0.f, o1 = 0.f, o2 = 0.f, o3 = 0.f;
            #pragma unroll
            for (int j2 = 0; j2 < SS; ++j2) {
                const float4 vv4 = kv4[KVV/4 + j2*2 + hh];
                const float pv = dt[j2];
                o0 += pv * vv4.x;
                o1 += pv * vv4.y;
                o2 += pv * vv4.z;
                o3 += pv * vv4.w;
            }
            float rs = 1.f / s;
            ov[hh*4+0] = o0*rs; ov[hh*4+1] = o1*rs;
            ov[hh*4+2] = o2*rs; ov[hh*4+3] = o3*rs;
        }

        if (lane < SS) {
            float o8[DD];
            #pragma unroll
            for (int d = 0; d < DD; ++d) {
                float acc = wb[256 + d];
                #pragma unroll
                for (int o2 = 0; o2 < HDIM; ++o2) acc += ov[o2] * wb[192 + d*8 + o2];
                o8[d] = acc;
            }
            gout[aown]   = make_float4(o8[0], o8[1], o8[2], o8[3]);
            gout[aown+1] = make_float4(o8[4], o8[5], o8[6], o8[7]);
        }
    }
}

// ---------------------------------------------------------------------------
// Encoder: h0 = relu(x*enc_w + enc_b) + pos_row[i] + pos_col[j], written to
// parity-0 in BOTH layouts. 128 blocks (one per batch) x 256 threads.
__global__ __launch_bounds__(256)
void axial_enc(const void* xv, const void* enc_wv, const void* enc_bv,
               const void* pos_rowv, const void* pos_colv, void* wsv)
{
    const bool isbf = sniff_bf(xv);
    float* G = (float*)wsv;
    __shared__ float eb[784];

    const int batch = blockIdx.x;
    const int tid   = threadIdx.x;

    float* b0 = G + (size_t)batch*GBAT;
    float4* row0 = (float4*)b0;  float4* col0 = (float4*)(b0 + RGN);

    for (int f = tid; f < 784; f += 256) {
        float v;
        if (f < 8)        v = ldsel(enc_wv, f, isbf);
        else if (f < 16)  v = ldsel(enc_bv, f-8, isbf);
        else if (f < 400) v = ldsel(pos_rowv, f-16, isbf);
        else              v = ldsel(pos_colv, f-400, isbf);
        eb[f] = v;
    }
    __syncthreads();

    for (int p = tid; p < PIX; p += 256) {
        const int i = p / SS, j = p % SS;
        const float xv2 = ldsel(xv, (long)batch*PIX + p, isbf);
        float hv[DD];
        #pragma unroll
        for (int d = 0; d < DD; ++d)
            hv[d] = fmaxf(0.f, xv2*eb[d] + eb[8+d]) + eb[16 + i*8 + d] + eb[400 + j*8 + d];
        const float4 a = make_float4(hv[0], hv[1], hv[2], hv[3]);
        const float4 b = make_float4(hv[4], hv[5], hv[6], hv[7]);
        col0[p*2] = a;              col0[p*2+1] = b;            // [i][j][d]
        row0[(j*SS+i)*2] = a;       row0[(j*SS+i)*2+1] = b;     // [j][i][d]
    }
}

// ---------------------------------------------------------------------------
// One layer, both axes: 512 blocks x 512 threads. Block = (batch, part);
// part 0-1 = row-attention halves, 2-3 = col-attention halves (24 problems
// per block, 3 per wave). Reads parity l&1, writes parity ~l&1. Kernel
// boundary = global barrier. Body in noinline attn_body_f (no-spill shape).
__global__ __launch_bounds__(PBDIM, 1)
void axial_phase(const void* xv, const void* Wqv, const void* Wkv,
                 const void* Wvv, const void* Wov, const void* bov,
                 void* wsv, int l)
{
    const bool isbf = sniff_bf(xv);
    float* G = (float*)wsv;

    __shared__ float kv[NWAV*KVW];
    __shared__ float wb[264];

    const int bid   = blockIdx.x;
    const int batch = bid & (NBAT-1);
    const int part  = bid >> 7;                 // 0..3
    const int axis  = part >> 1;                // 0: row, 1: col
    const int pbase = (part & 1) * 24;          // half of 48 problems
    const int tid   = threadIdx.x;
    const int lane  = tid & 63;
    const int wav   = tid >> 6;                 // 0..7
    const int tl    = lane < SS ? lane : SS-1;
    float* kvw = kv + wav*KVW;

    float* b0 = G + (size_t)batch*GBAT;
    float* b1 = G + BUFSZ + (size_t)batch*GBAT;
    float4* row0 = (float4*)b0;  float4* col0 = (float4*)(b0 + RGN);
    float4* row1 = (float4*)b1;  float4* col1 = (float4*)(b1 + RGN);

    const int la = l*2 + axis;
    for (int f = tid; f < 264; f += PBDIM) {
        float v;
        if (f < 64)       v = ldsel(Wqv, la*64 + f, isbf);
        else if (f < 128) v = ldsel(Wkv, la*64 + f-64, isbf);
        else if (f < 192) v = ldsel(Wvv, la*64 + f-128, isbf);
        else if (f < 256) v = ldsel(Wov, la*64 + f-192, isbf);
        else              v = ldsel(bov, la*8 + f-256, isbf);
        wb[f] = v;
    }
    __syncthreads();

    const int par = l & 1;
    float4* rin  = par ? row1 : row0;  float4* cin  = par ? col1 : col0;
    float4* rout = par ? row0 : row1;  float4* cout = par ? col0 : col1;
    const float4* own = axis ? (const float4*)cin : (const float4*)rin;
    const float4* oth = axis ? (const float4*)rin : (const float4*)cin;
    float4* gout = axis ? cout : rout;

    if (l == 0) attn_body_f<1>(own, oth, gout, kvw, wb, pbase, wav, lane, tl);
    else        attn_body_f<0>(own, oth, gout, kvw, wb, pbase, wav, lane, tl);
}

// ---------------------------------------------------------------------------
// Classifier: final h = relu(row+col) of parity 0 (layer 7 wrote parity 0);
// max over d, dot with cls_w, softmax. 128 blocks x 256 threads.
__global__ __launch_bounds__(256)
void axial_cls(const void* xv, const void* cls_wv, const void* cls_bv,
               void* outv, void* wsv)
{
    const bool isbf = sniff_bf(xv);
    float* G = (float*)wsv;
    __shared__ float cb[NC];

    const int batch = blockIdx.x;
    const int tid   = threadIdx.x;
    const int lane  = tid & 63;

    float* b0 = G + (size_t)batch*GBAT;
    float4* row0 = (float4*)b0;  float4* col0 = (float4*)(b0 + RGN);

    if (tid < NC) cb[tid] = ldsel(cls_bv, tid, isbf);
    __syncthreads();

    float pacc[NC] = {0.f,0.f,0.f,0.f,0.f,0.f,0.f};
    const float* cwf = (const float*)cls_wv;
    const __hip_bfloat16* cwb = (const __hip_bfloat16*)cls_wv;
    for (int p = tid; p < PIX; p += 256) {
        const int i = p / SS, j = p % SS;
        const float4 c0 = col0[p*2], c1 = col0[p*2+1];
        const float4 r0 = row0[(j*SS+i)*2], r1 = row0[(j*SS+i)*2+1];
        float mv =     fmaxf(0.f, c0.x + r0.x);
        mv = fmaxf(mv, fmaxf(0.f, c0.y + r0.y));
        mv = fmaxf(mv, fmaxf(0.f, c0.z + r0.z));
        mv = fmaxf(mv, fmaxf(0.f, c0.w + r0.w));
        mv = fmaxf(mv, fmaxf(0.f, c1.x + r1.x));
        mv = fmaxf(mv, fmaxf(0.f, c1.y + r1.y));
        mv = fmaxf(mv, fmaxf(0.f, c1.z + r1.z));
        mv = fmaxf(mv, fmaxf(0.f, c1.w + r1.w));
        if (isbf) {
            #pragma unroll
            for (int c = 0; c < NC; ++c) pacc[c] += mv * __bfloat162float(cwb[c*PIX + p]);
        } else {
            #pragma unroll
            for (int c = 0; c < NC; ++c) pacc[c] += mv * cwf[c*PIX + p];
        }
    }
    #pragma unroll
    for (int c = 0; c < NC; ++c) {
        #pragma unroll
        for (int off = 32; off > 0; off >>= 1) pacc[c] += __shfl_down(pacc[c], off, 64);
    }
    if (lane == 0) {
        #pragma unroll
        for (int c = 0; c < NC; ++c) atomicAdd(&cb[c], pacc[c]);
    }
    __syncthreads();

    if (tid < NC) {
        float m = cb[0];
        #pragma unroll
        for (int c = 1; c < NC; ++c) m = fmaxf(m, cb[c]);
        float s = 0.f;
        #pragma unroll
        for (int c = 0; c < NC; ++c) s += exp2f((cb[c]-m) * 1.44269504089f);
        const float e = exp2f((cb[tid]-m) * 1.44269504089f);
        const float r = e / s;
        if (isbf) ((__hip_bfloat16*)outv)[batch*NC + tid] = __float2bfloat16(r);
        else      ((float*)outv)[batch*NC + tid] = r;
    }
}

extern "C" void kernel_launch(void* const* d_in, const int* in_sizes, int n_in,
                              void* d_out, int out_size, void* d_ws, size_t ws_size,
                              hipStream_t stream) {
    (void)in_sizes; (void)n_in; (void)ws_size; (void)out_size;
    // d_ws: 2 parity buffers = 2*BUFSZ*4 ~= 37.75 MB (present since R5).
    // Kernel boundaries provide all inter-phase synchronization (stream order).
    axial_enc<<<dim3(NBAT), dim3(256), 0, stream>>>(
        d_in[0], d_in[1], d_in[2], d_in[3], d_in[4], d_ws);
    for (int l = 0; l < NL; ++l) {
        axial_phase<<<dim3(4*NBAT), dim3(PBDIM), 0, stream>>>(
            d_in[0], d_in[5], d_in[6], d_in[7], d_in[8], d_in[9], d_ws, l);
    }
    axial_cls<<<dim3(NBAT), dim3(256), 0, stream>>>(
        d_in[0], d_in[10], d_in[11], d_out, d_ws);
}

// Round 20
// 800.785 us; speedup vs baseline: 2.0079x; 2.0079x over previous
//
#include <hip/hip_runtime.h>
#include <hip/hip_bf16.h>

// R20: R14 (770us, the ONLY clean-counter build: FETCH 10.4MB, WRITE exactly
// logical, 204 VGPR natural, 90us/phase) + software-pipelined input loads.
// The 4-round spill saga's conclusion: this body's honest demand is ~204
// regs; every cap and every noinline wrapper spills (noinline device fns
// compile against a default ~128-reg ABI budget and spill internally --
// explains the old cooperative builds' 3-4x logical WRITE too). So occupancy
// is closed; attack R14's measured stall instead: VALUBusy 48% at 2
// waves/SIMD, with each "#pragma unroll 1" iteration exposing ~200-400cyc of
// L2 latency on 4 dependent loads (oth 48-way scattered) feeding ht.
// Transform (R9-proven-correct, R9-failed only on the 128-cap): unroll the
// 3-problem loop straight-line, issue P1's loads before body(P0) and P2's
// before body(P1). Headroom: 204+~32 staged regs = ~236 < cap 256.
// Gates: VGPR <256 AND per-phase FETCH ~10-25MB / WRITE ~18.4MB; any
// ballooning = spill -> revert to R14 verbatim. enc/cls untouched.
#define NBAT 128
#define SS   48
#define DD   8
#define HDIM 8
#define NL   8
#define NC   7
#define PIX  (SS*SS)
#define RGN  (PIX*DD)            // one exchange region: 18432 floats
#define GBAT (2*RGN)             // row+col regions per batch
#define BUFSZ ((size_t)NBAT*GBAT)      // one parity buffer (floats)
#define KVV  384
#define KVW  768

__device__ __forceinline__ float ldsel(const void* p, long i, bool bf) {
    return bf ? __bfloat162float(((const __hip_bfloat16*)p)[i])
              : ((const float*)p)[i];
}

__device__ __forceinline__ bool sniff_bf(const void* xv) {
    const unsigned* xu = (const unsigned*)xv;
    int cnt = 0;
    #pragma unroll
    for (int t = 0; t < 32; ++t) {
        const unsigned w = xu[t];
        const int e = (w >> 7) & 0xff;
        cnt += (e > 100 && e < 150) ? 1 : 0;
    }
    return cnt >= 20;
}

// ---------------------------------------------------------------------------
// Encoder: h0 = relu(x*enc_w + enc_b) + pos_row[i] + pos_col[j], written to
// parity-0 in BOTH layouts. 128 blocks (one per batch) x 256 threads.
__global__ __launch_bounds__(256)
void axial_enc(const void* xv, const void* enc_wv, const void* enc_bv,
               const void* pos_rowv, const void* pos_colv, void* wsv)
{
    const bool isbf = sniff_bf(xv);
    float* G = (float*)wsv;
    __shared__ float eb[784];

    const int batch = blockIdx.x;
    const int tid   = threadIdx.x;

    float* b0 = G + (size_t)batch*GBAT;
    float4* row0 = (float4*)b0;  float4* col0 = (float4*)(b0 + RGN);

    for (int f = tid; f < 784; f += 256) {
        float v;
        if (f < 8)        v = ldsel(enc_wv, f, isbf);
        else if (f < 16)  v = ldsel(enc_bv, f-8, isbf);
        else if (f < 400) v = ldsel(pos_rowv, f-16, isbf);
        else              v = ldsel(pos_colv, f-400, isbf);
        eb[f] = v;
    }
    __syncthreads();

    for (int p = tid; p < PIX; p += 256) {
        const int i = p / SS, j = p % SS;
        const float xv2 = ldsel(xv, (long)batch*PIX + p, isbf);
        float hv[DD];
        #pragma unroll
        for (int d = 0; d < DD; ++d)
            hv[d] = fmaxf(0.f, xv2*eb[d] + eb[8+d]) + eb[16 + i*8 + d] + eb[400 + j*8 + d];
        const float4 a = make_float4(hv[0], hv[1], hv[2], hv[3]);
        const float4 b = make_float4(hv[4], hv[5], hv[6], hv[7]);
        col0[p*2] = a;              col0[p*2+1] = b;            // [i][j][d]
        row0[(j*SS+i)*2] = a;       row0[(j*SS+i)*2+1] = b;     // [j][i][d]
    }
}

// ---------------------------------------------------------------------------
// One problem's attention body; inputs arrive as preloaded registers so the
// caller can issue the NEXT problem's loads behind this compute.
// first=1: ht = h0 as-is; else ht = relu(own + oth).
__device__ __forceinline__
void attn_one(int prob, float4 o0, float4 o1, float4 t0, float4 t1, bool first,
              float4* __restrict__ gout, float* __restrict__ kvw,
              const float* __restrict__ wb, int lane, int tl)
{
    const float4* kv4 = reinterpret_cast<const float4*>(kvw);

    float ht[DD];
    if (first) {
        ht[0]=o0.x; ht[1]=o0.y; ht[2]=o0.z; ht[3]=o0.w;
        ht[4]=o1.x; ht[5]=o1.y; ht[6]=o1.z; ht[7]=o1.w;
    } else {
        ht[0]=fmaxf(0.f,o0.x+t0.x); ht[1]=fmaxf(0.f,o0.y+t0.y);
        ht[2]=fmaxf(0.f,o0.z+t0.z); ht[3]=fmaxf(0.f,o0.w+t0.w);
        ht[4]=fmaxf(0.f,o1.x+t1.x); ht[5]=fmaxf(0.f,o1.y+t1.y);
        ht[6]=fmaxf(0.f,o1.z+t1.z); ht[7]=fmaxf(0.f,o1.w+t1.w);
    }

    // q/k/v projections; fold 0.5 (E^-0.5) * log2(e) into q for exp2.
    float q[HDIM];
    {
        float kk[HDIM], vv[HDIM];
        #pragma unroll
        for (int o = 0; o < HDIM; ++o) {
            float aq = 0.f, ak = 0.f, av = 0.f;
            #pragma unroll
            for (int d = 0; d < DD; ++d) {
                aq += ht[d] * wb[o*8 + d];
                ak += ht[d] * wb[64 + o*8 + d];
                av += ht[d] * wb[128 + o*8 + d];
            }
            q[o] = aq * 0.72134752044f;  // 0.5 * log2(e)
            kk[o] = ak; vv[o] = av;
        }
        if (lane < SS) {   // lanes 48-63 would duplicate token 47: skip
            float4* kp = reinterpret_cast<float4*>(kvw + tl*8);
            kp[0] = make_float4(kk[0], kk[1], kk[2], kk[3]);
            kp[1] = make_float4(kk[4], kk[5], kk[6], kk[7]);
            float4* vp = reinterpret_cast<float4*>(kvw + KVV + tl*8);
            vp[0] = make_float4(vv[0], vv[1], vv[2], vv[3]);
            vp[1] = make_float4(vv[4], vv[5], vv[6], vv[7]);
        }
    }

    float ov[HDIM];
    #pragma unroll
    for (int hh = 0; hh < 2; ++hh) {
        float dt[SS];
        #pragma unroll
        for (int j2 = 0; j2 < SS; ++j2) {
            const float4 kk4 = kv4[j2*2 + hh];       // LDS same-addr broadcast
            float acc =  q[hh*4+0] * kk4.x;
            acc       += q[hh*4+1] * kk4.y;
            acc       += q[hh*4+2] * kk4.z;
            acc       += q[hh*4+3] * kk4.w;
            dt[j2] = acc;
        }
        // max tree (fmax exactly associative -> bitwise same as chain)
        float mt[24];
        #pragma unroll
        for (int t2 = 0; t2 < 24; ++t2) mt[t2] = fmaxf(dt[t2], dt[t2+24]);
        #pragma unroll
        for (int t2 = 0; t2 < 12; ++t2) mt[t2] = fmaxf(mt[t2], mt[t2+12]);
        #pragma unroll
        for (int t2 = 0; t2 < 6; ++t2)  mt[t2] = fmaxf(mt[t2], mt[t2+6]);
        #pragma unroll
        for (int t2 = 0; t2 < 3; ++t2)  mt[t2] = fmaxf(mt[t2], mt[t2+3]);
        const float m = fmaxf(fmaxf(mt[0], mt[1]), mt[2]);
        float s = 0.f;
        #pragma unroll
        for (int j2 = 0; j2 < SS; ++j2) {
            float pv = exp2f(dt[j2] - m);
            dt[j2] = pv; s += pv;
        }
        float o0a = 0.f, o1a = 0.f, o2a = 0.f, o3a = 0.f;
        #pragma unroll
        for (int j2 = 0; j2 < SS; ++j2) {
            const float4 vv4 = kv4[KVV/4 + j2*2 + hh];
            const float pv = dt[j2];
            o0a += pv * vv4.x;
            o1a += pv * vv4.y;
            o2a += pv * vv4.z;
            o3a += pv * vv4.w;
        }
        float rs = 1.f / s;
        ov[hh*4+0] = o0a*rs; ov[hh*4+1] = o1a*rs;
        ov[hh*4+2] = o2a*rs; ov[hh*4+3] = o3a*rs;
    }

    if (lane < SS) {
        float o8[DD];
        #pragma unroll
        for (int d = 0; d < DD; ++d) {
            float acc = wb[256 + d];
            #pragma unroll
            for (int o2 = 0; o2 < HDIM; ++o2) acc += ov[o2] * wb[192 + d*8 + o2];
            o8[d] = acc;
        }
        const int aown = (prob*SS + tl)*2;
        gout[aown]   = make_float4(o8[0], o8[1], o8[2], o8[3]);
        gout[aown+1] = make_float4(o8[4], o8[5], o8[6], o8[7]);
    }
}

// ---------------------------------------------------------------------------
// One layer, both axes: 1024 blocks x 256 threads. Block = (batch, part);
// part 0-3 = row-attention quarters, 4-7 = col-attention quarters.
// Reads parity l&1 (own coalesced (prob*SS+tl), oth scattered (tl*SS+prob)),
// writes own-layout region of parity ~l&1. relu(own+oth) fused at input
// (l>0); l==0 reads h0 as-is. Kernel boundary = global barrier (no flags).
// Straight-line 3-problem software pipeline: P1's loads issue before
// body(P0), P2's before body(P1) -- L2 latency hides under ~2600cyc bodies.
__global__ __launch_bounds__(256)
void axial_phase(const void* xv, const void* Wqv, const void* Wkv,
                 const void* Wvv, const void* Wov, const void* bov,
                 void* wsv, int l)
{
    const bool isbf = sniff_bf(xv);
    float* G = (float*)wsv;

    __shared__ float kv[4*KVW];
    __shared__ float wb[264];

    const int bid   = blockIdx.x;
    const int batch = bid & (NBAT-1);
    const int part  = bid >> 7;                 // 0..7
    const int axis  = part >> 2;                // 0: row, 1: col
    const int pbase = (part & 3) * 12;          // quarter of 48 problems
    const int tid   = threadIdx.x;
    const int lane  = tid & 63;
    const int wav   = tid >> 6;                 // 0..3
    const int tl    = lane < SS ? lane : SS-1;
    float* kvw = kv + wav*KVW;

    float* b0 = G + (size_t)batch*GBAT;
    float* b1 = G + BUFSZ + (size_t)batch*GBAT;
    float4* row0 = (float4*)b0;  float4* col0 = (float4*)(b0 + RGN);
    float4* row1 = (float4*)b1;  float4* col1 = (float4*)(b1 + RGN);

    const int la = l*2 + axis;
    for (int f = tid; f < 264; f += 256) {
        float v;
        if (f < 64)       v = ldsel(Wqv, la*64 + f, isbf);
        else if (f < 128) v = ldsel(Wkv, la*64 + f-64, isbf);
        else if (f < 192) v = ldsel(Wvv, la*64 + f-128, isbf);
        else if (f < 256) v = ldsel(Wov, la*64 + f-192, isbf);
        else              v = ldsel(bov, la*8 + f-256, isbf);
        wb[f] = v;
    }
    __syncthreads();

    const int par = l & 1;
    float4* rin  = par ? row1 : row0;  float4* cin  = par ? col1 : col0;
    float4* rout = par ? row0 : row1;  float4* cout = par ? col0 : col1;
    const float4* own = axis ? (const float4*)cin : (const float4*)rin;
    const float4* oth = axis ? (const float4*)rin : (const float4*)cin;
    float4* gout = axis ? cout : rout;
    const bool first = (l == 0);

    const int prob0 = pbase + wav;          // 3 problems per wave (NWAV=4)
    const int prob1 = prob0 + 4;
    const int prob2 = prob0 + 8;

    const float4 z = make_float4(0.f, 0.f, 0.f, 0.f);
    float4 A0, A1, AT0 = z, AT1 = z;
    float4 B0, B1, BT0 = z, BT1 = z;
    float4 C0, C1, CT0 = z, CT1 = z;

    {   // load P0
        const int a = (prob0*SS + tl)*2;
        A0 = own[a]; A1 = own[a+1];
        if (!first) { const int b = (tl*SS + prob0)*2; AT0 = oth[b]; AT1 = oth[b+1]; }
    }
    {   // issue P1 (in flight across body(P0))
        const int a = (prob1*SS + tl)*2;
        B0 = own[a]; B1 = own[a+1];
        if (!first) { const int b = (tl*SS + prob1)*2; BT0 = oth[b]; BT1 = oth[b+1]; }
    }
    attn_one(prob0, A0, A1, AT0, AT1, first, gout, kvw, wb, lane, tl);
    {   // issue P2 (in flight across body(P1))
        const int a = (prob2*SS + tl)*2;
        C0 = own[a]; C1 = own[a+1];
        if (!first) { const int b = (tl*SS + prob2)*2; CT0 = oth[b]; CT1 = oth[b+1]; }
    }
    attn_one(prob1, B0, B1, BT0, BT1, first, gout, kvw, wb, lane, tl);
    attn_one(prob2, C0, C1, CT0, CT1, first, gout, kvw, wb, lane, tl);
}

// ---------------------------------------------------------------------------
// Classifier: final h = relu(row+col) of parity 0 (layer 7 wrote parity 0);
// max over d, dot with cls_w, softmax. 128 blocks x 256 threads.
__global__ __launch_bounds__(256)
void axial_cls(const void* xv, const void* cls_wv, const void* cls_bv,
               void* outv, void* wsv)
{
    const bool isbf = sniff_bf(xv);
    float* G = (float*)wsv;
    __shared__ float cb[NC];

    const int batch = blockIdx.x;
    const int tid   = threadIdx.x;
    const int lane  = tid & 63;

    float* b0 = G + (size_t)batch*GBAT;
    float4* row0 = (float4*)b0;  float4* col0 = (float4*)(b0 + RGN);

    if (tid < NC) cb[tid] = ldsel(cls_bv, tid, isbf);
    __syncthreads();

    float pacc[NC] = {0.f,0.f,0.f,0.f,0.f,0.f,0.f};
    const float* cwf = (const float*)cls_wv;
    const __hip_bfloat16* cwb = (const __hip_bfloat16*)cls_wv;
    for (int p = tid; p < PIX; p += 256) {
        const int i = p / SS, j = p % SS;
        const float4 c0 = col0[p*2], c1 = col0[p*2+1];
        const float4 r0 = row0[(j*SS+i)*2], r1 = row0[(j*SS+i)*2+1];
        float mv =     fmaxf(0.f, c0.x + r0.x);
        mv = fmaxf(mv, fmaxf(0.f, c0.y + r0.y));
        mv = fmaxf(mv, fmaxf(0.f, c0.z + r0.z));
        mv = fmaxf(mv, fmaxf(0.f, c0.w + r0.w));
        mv = fmaxf(mv, fmaxf(0.f, c1.x + r1.x));
        mv = fmaxf(mv, fmaxf(0.f, c1.y + r1.y));
        mv = fmaxf(mv, fmaxf(0.f, c1.z + r1.z));
        mv = fmaxf(mv, fmaxf(0.f, c1.w + r1.w));
        if (isbf) {
            #pragma unroll
            for (int c = 0; c < NC; ++c) pacc[c] += mv * __bfloat162float(cwb[c*PIX + p]);
        } else {
            #pragma unroll
            for (int c = 0; c < NC; ++c) pacc[c] += mv * cwf[c*PIX + p];
        }
    }
    #pragma unroll
    for (int c = 0; c < NC; ++c) {
        #pragma unroll
        for (int off = 32; off > 0; off >>= 1) pacc[c] += __shfl_down(pacc[c], off, 64);
    }
    if (lane == 0) {
        #pragma unroll
        for (int c = 0; c < NC; ++c) atomicAdd(&cb[c], pacc[c]);
    }
    __syncthreads();

    if (tid < NC) {
        float m = cb[0];
        #pragma unroll
        for (int c = 1; c < NC; ++c) m = fmaxf(m, cb[c]);
        float s = 0.f;
        #pragma unroll
        for (int c = 0; c < NC; ++c) s += exp2f((cb[c]-m) * 1.44269504089f);
        const float e = exp2f((cb[tid]-m) * 1.44269504089f);
        const float r = e / s;
        if (isbf) ((__hip_bfloat16*)outv)[batch*NC + tid] = __float2bfloat16(r);
        else      ((float*)outv)[batch*NC + tid] = r;
    }
}

extern "C" void kernel_launch(void* const* d_in, const int* in_sizes, int n_in,
                              void* d_out, int out_size, void* d_ws, size_t ws_size,
                              hipStream_t stream) {
    (void)in_sizes; (void)n_in; (void)ws_size; (void)out_size;
    // d_ws: 2 parity buffers = 2*BUFSZ*4 ~= 37.75 MB (present since R5).
    // Kernel boundaries provide all inter-phase synchronization (stream order).
    axial_enc<<<dim3(NBAT), dim3(256), 0, stream>>>(
        d_in[0], d_in[1], d_in[2], d_in[3], d_in[4], d_ws);
    for (int l = 0; l < NL; ++l) {
        axial_phase<<<dim3(8*NBAT), dim3(256), 0, stream>>>(
            d_in[0], d_in[5], d_in[6], d_in[7], d_in[8], d_in[9], d_ws, l);
    }
    axial_cls<<<dim3(NBAT), dim3(256), 0, stream>>>(
        d_in[0], d_in[10], d_in[11], d_out, d_ws);
}